// Round 11
// baseline (390.338 us; speedup 1.0000x reference)
//
#include <hip/hip_runtime.h>
#include <hip/hip_fp16.h>
#include <cmath>

#define T_TOKENS 8192
#define HID 2048
#define NEXP 8
#define INTERM 1024
#define GATE_NB 2048
#define MAX_TT 136
#define MAX_TT2 72
#define GEMM1_NB 1024       // gemm1 persistent blocks: 4 per CU (32KB LDS each)
#define GEMM2_NB 256        // gemm2 persistent blocks: 1 per CU (128KB LDS)

typedef _Float16 f16x8 __attribute__((ext_vector_type(8)));
typedef _Float16 f16x4 __attribute__((ext_vector_type(4)));
typedef float f32x4 __attribute__((ext_vector_type(4)));

static __device__ __forceinline__ float gelu_tanh(float v) {
    return 0.5f * v * (1.0f + tanhf(0.79788456080286535588f * (v + 0.044715f * v * v * v)));
}

static __device__ __forceinline__ void glds16(const void* g, void* l) {
    __builtin_amdgcn_global_load_lds((const __attribute__((address_space(1))) void*)g,
                                     (__attribute__((address_space(3))) void*)l, 16, 0, 0);
}

// 128B-row tiles (BK=64): phys 16B-chunk = chunk ^ (row&7)
static __device__ __forceinline__ f16x8 lds_read(const _Float16* base, int row, int chunk) {
    int phys = chunk ^ (row & 7);
    return *reinterpret_cast<const f16x8*>(
        reinterpret_cast<const char*>(base) + row * 128 + phys * 16);
}

// 64B-row tiles (BK=32): phys 16B-chunk = chunk ^ ((row>>1)&3)  [R8-verified, 0 conflicts]
static __device__ __forceinline__ f16x8 lds_read32(const _Float16* base, int row, int chunk) {
    int phys = chunk ^ ((row >> 1) & 3);
    return *reinterpret_cast<const f16x8*>(
        reinterpret_cast<const char*>(base) + row * 64 + phys * 16);
}

// ------------- tconv body: fp32 [Z][R][C] -> fp16 [Z][C][R] -------------
static __device__ __forceinline__ void tconv_body(const float* __restrict__ in,
                                                  _Float16* __restrict__ out,
                                                  int R, int C, int bx, int by, int bz) {
    __shared__ float t[32][33];
    int r0 = by * 32, c0 = bx * 32;
    int tid = threadIdx.x;
    int r = tid >> 3, c4 = (tid & 7) * 4;
    const float4 v = *reinterpret_cast<const float4*>(&in[((size_t)bz * R + (r0 + r)) * C + c0 + c4]);
    t[r][c4 + 0] = v.x; t[r][c4 + 1] = v.y; t[r][c4 + 2] = v.z; t[r][c4 + 3] = v.w;
    __syncthreads();
    int oc = tid >> 3;
    int or4 = (tid & 7) * 4;
    f16x4 o;
    o[0] = (_Float16)t[or4 + 0][oc];
    o[1] = (_Float16)t[or4 + 1][oc];
    o[2] = (_Float16)t[or4 + 2][oc];
    o[3] = (_Float16)t[or4 + 3][oc];
    *reinterpret_cast<f16x4*>(&out[((size_t)bz * C + (c0 + oc)) * R + r0 + or4]) = o;
}

// -------- gate body: one wave per token; emits xh = fp16(x) --------
static __device__ __forceinline__ void gate_body(const float* __restrict__ x,
                                                 const float* __restrict__ gw,
                                                 _Float16* __restrict__ xh,
                                                 int* __restrict__ tk_idx, float* __restrict__ tk_w,
                                                 int* __restrict__ part_cnt,
                                                 double* __restrict__ part_sumP, int gid) {
    __shared__ double sds[4][NEXP];
    __shared__ int sci[4][NEXP];
    int w = threadIdx.x >> 6;
    int lane = threadIdx.x & 63;
    int t = gid * 4 + w;

    const float4* xr = (const float4*)(x + (size_t)t * HID);
    _Float16* xo = xh + (size_t)t * HID;
    double acc[NEXP];
#pragma unroll
    for (int e = 0; e < NEXP; e++) acc[e] = 0.0;
#pragma unroll
    for (int i = 0; i < HID / 256; i++) {
        float4 xv = xr[i * 64 + lane];
        f16x4 h;
        h[0] = (_Float16)xv.x; h[1] = (_Float16)xv.y;
        h[2] = (_Float16)xv.z; h[3] = (_Float16)xv.w;
        *reinterpret_cast<f16x4*>(xo + i * 256 + lane * 4) = h;
#pragma unroll
        for (int e = 0; e < NEXP; e++) {
            float4 gv = ((const float4*)(gw + (size_t)e * HID))[i * 64 + lane];
            acc[e] += (double)xv.x * (double)gv.x + (double)xv.y * (double)gv.y
                    + (double)xv.z * (double)gv.z + (double)xv.w * (double)gv.w;
        }
    }
#pragma unroll
    for (int e = 0; e < NEXP; e++) {
#pragma unroll
        for (int off = 32; off > 0; off >>= 1) acc[e] += __shfl_xor(acc[e], off, 64);
    }
    double mx = acc[0];
#pragma unroll
    for (int e = 1; e < NEXP; e++) mx = acc[e] > mx ? acc[e] : mx;
    double ex[NEXP];
    double sum = 0.0;
#pragma unroll
    for (int e = 0; e < NEXP; e++) { ex[e] = exp(acc[e] - mx); sum += ex[e]; }
    int i0 = 0;
#pragma unroll
    for (int e = 1; e < NEXP; e++) if (ex[e] > ex[i0]) i0 = e;
    int i1 = (i0 == 0) ? 1 : 0;
#pragma unroll
    for (int e = 0; e < NEXP; e++) if (e != i0 && ex[e] > ex[i1]) i1 = e;
    double p0 = ex[i0], p1 = ex[i1];
    double t2 = p0 + p1;
    if (lane == 0) {
        tk_idx[2 * t] = i0; tk_idx[2 * t + 1] = i1;
        tk_w[2 * t] = (float)(p0 / t2); tk_w[2 * t + 1] = (float)(p1 / t2);
#pragma unroll
        for (int e = 0; e < NEXP; e++) {
            sds[w][e] = ex[e] / sum;
            sci[w][e] = (e == i0 ? 1 : 0) + (e == i1 ? 1 : 0);
        }
    }
    __syncthreads();
    if (threadIdx.x < NEXP) {
        int e = threadIdx.x;
        part_sumP[e * GATE_NB + gid] = sds[0][e] + sds[1][e] + sds[2][e] + sds[3][e];
        part_cnt[e * GATE_NB + gid]  = sci[0][e] + sci[1][e] + sci[2][e] + sci[3][e];
    }
}

// -------- fused prep: [0,16384) tconv w1, [16384,32768) tconv w2, [32768,34816) gate --------
__global__ __launch_bounds__(256) void prep_kernel(const float* __restrict__ x,
                                                   const float* __restrict__ gw,
                                                   const float* __restrict__ w1,
                                                   const float* __restrict__ w2,
                                                   _Float16* __restrict__ xh,
                                                   _Float16* __restrict__ w1t,
                                                   _Float16* __restrict__ w2t,
                                                   int* __restrict__ tk_idx, float* __restrict__ tk_w,
                                                   int* __restrict__ part_cnt,
                                                   double* __restrict__ part_sumP) {
    int bid = blockIdx.x;
    if (bid < 16384) {
        int bx = bid & 31, by = (bid >> 5) & 63, bz = bid >> 11;
        tconv_body(w1, w1t, HID, INTERM, bx, by, bz);
    } else if (bid < 32768) {
        int r = bid - 16384;
        int bx = r & 63, by = (r >> 6) & 31, bz = r >> 11;
        tconv_body(w2, w2t, INTERM, HID, bx, by, bz);
    } else {
        gate_body(x, gw, xh, tk_idx, tk_w, part_cnt, part_sumP, bid - 32768);
    }
}

// ------- reduce partials, offsets, aux, cursor, tile tables (BM=128 & 256), steal ctrs -------
__global__ __launch_bounds__(256) void finalize_kernel(const int* __restrict__ part_cnt,
                                                       const double* __restrict__ part_sumP,
                                                       int* __restrict__ cnt, int* __restrict__ offs,
                                                       int* __restrict__ cursor,
                                                       int* __restrict__ ttab,
                                                       int* __restrict__ ttab2,
                                                       int* __restrict__ nmt,
                                                       int* __restrict__ steal,
                                                       float* __restrict__ aux_out) {
    __shared__ double swv[4];
    __shared__ int cwv[4];
    __shared__ double sE[NEXP];
    __shared__ int cE[NEXP];
    int w = threadIdx.x >> 6;
    int lane = threadIdx.x & 63;
    for (int e = 0; e < NEXP; e++) {
        double s = 0.0; int c = 0;
        for (int j = threadIdx.x; j < GATE_NB; j += 256) {
            s += part_sumP[e * GATE_NB + j];
            c += part_cnt[e * GATE_NB + j];
        }
#pragma unroll
        for (int off = 32; off > 0; off >>= 1) {
            s += __shfl_xor(s, off, 64);
            c += __shfl_xor(c, off, 64);
        }
        if (lane == 0) { swv[w] = s; cwv[w] = c; }
        __syncthreads();
        if (threadIdx.x == 0) {
            sE[e] = swv[0] + swv[1] + swv[2] + swv[3];
            cE[e] = cwv[0] + cwv[1] + cwv[2] + cwv[3];
        }
        __syncthreads();
    }
    if (threadIdx.x == 0) {
        int off = 0;
        double aux = 0.0;
        int idx = 0, idx2 = 0;
#pragma unroll
        for (int e = 0; e < NEXP; e++) {
            cnt[e] = cE[e];
            offs[e] = off;
            off += cE[e];
            cursor[e] = 0;
            aux += ((double)cE[e] / (double)T_TOKENS) * (sE[e] / (double)T_TOKENS);
            int mt = (cE[e] + 127) >> 7;
            for (int m = 0; m < mt; m++) ttab[idx++] = (e << 16) | m;
            int mt2 = (cE[e] + 255) >> 8;
            for (int m = 0; m < mt2; m++) ttab2[idx2++] = (e << 16) | m;
        }
        nmt[0] = idx;
        nmt[1] = idx2;
        for (; idx < MAX_TT; idx++) ttab[idx] = -1;
        for (; idx2 < MAX_TT2; idx2++) ttab2[idx2] = -1;
        for (int i = 0; i < 16; i++) steal[i] = 0;
        aux_out[0] = (float)(0.01 * (double)NEXP * aux);
    }
}

// ------- build per-expert row lists + inverse map (wave-aggregated atomics) -------
__global__ void scatter_kernel(const int* __restrict__ tk_idx, const float* __restrict__ tk_w,
                               const int* __restrict__ offs, int* __restrict__ cursor,
                               int* __restrict__ row_tok, float* __restrict__ row_w,
                               int* __restrict__ tok_row) {
    int t = blockIdx.x * blockDim.x + threadIdx.x;
    int lane = threadIdx.x & 63;
    unsigned long long below = (lane == 0) ? 0ull : ((~0ull) >> (64 - lane));
    for (int k = 0; k < 2; k++) {
        int e = tk_idx[2 * t + k];
        float wv = tk_w[2 * t + k];
        int pos = 0;
#pragma unroll
        for (int ee = 0; ee < NEXP; ee++) {
            unsigned long long m = __ballot(e == ee);
            if (e == ee) {
                int rank = (int)__popcll(m & below);
                int leader = (int)__ffsll((unsigned long long)m) - 1;
                int b = 0;
                if (lane == leader) b = atomicAdd(&cursor[ee], (int)__popcll(m));
                b = __shfl(b, leader, 64);
                pos = b + rank;
            }
        }
        int r = offs[e] + pos;
        row_tok[r] = t;
        row_w[r] = wv;
        tok_row[2 * t + k] = r;
    }
}

// ====== GEMM1: 128x128 tile, BK=32, 4 waves, 32KB LDS -> 4 blocks/CU, XCD steal ======
// Per K-tile: STAGE next slot (4 glds/wave) -> counted vmcnt(4) -> barrier ->
// 8 ds_read + 16 MFMA (compiler-scheduled) -> lgkmcnt(0) -> barrier.
// High TLP (16 waves/CU) hides the per-tile latency the 2-block version stalled on.
template<bool GATHER, bool GELU, int KTOT, int NX>
__global__ __launch_bounds__(256, 4) void gemmf_kernel(
    const _Float16* __restrict__ Aglob,
    const _Float16* __restrict__ Bglob,
    const int* __restrict__ cnt, const int* __restrict__ offs,
    const int* __restrict__ row_tok,
    const int* __restrict__ ttab,
    const int* __restrict__ nmt,
    int* __restrict__ steal,
    _Float16* __restrict__ Out, int Ncols)
{
    constexpr int NT = KTOT / 32;
    __shared__ __align__(16) _Float16 As[2][128][32];   // 16KB
    __shared__ __align__(16) _Float16 Bs[2][128][32];   // 16KB
    __shared__ int s_it;

    int tid = threadIdx.x;
    int w = tid >> 6, lane = tid & 63;
    int wr = w >> 1, wc = w & 1;          // 2x2 wave grid, wave-tile 64x64
    int fr = lane & 15, fq = lane >> 4;

    int n_items = nmt[0] * NX;
    int chunk = (n_items + 7) >> 3;
    int xcd = blockIdx.x & 7;

    int srow = lane >> 2;                  // 0..15 row within one glds (64B rows)
    int lc = (lane & 3) ^ ((lane >> 3) & 3);   // pre-swizzled 16B chunk

    _Float16* ldsA = &As[0][0][0] + w * 1024;  // wave stages A rows [32w,32w+32)
    _Float16* ldsB = &Bs[0][0][0] + w * 1024;

    for (;;) {
        __syncthreads();
        if (tid == 0) s_it = atomicAdd(&steal[xcd], 1);
        __syncthreads();
        int i = s_it;
        if (i >= chunk) break;
        int it = xcd * chunk + i;
        if (it >= n_items) break;

        int ent = ttab[it / NX];
        int e = ent >> 16;
        int m0 = (ent & 0xffff) << 7;
        int Ne = cnt[e];
        int base = offs[e];
        int n0 = (it & (NX - 1)) << 7;

        const _Float16* aS[2];
#pragma unroll
        for (int g = 0; g < 2; g++) {
            int ar = m0 + w * 32 + g * 16 + srow; if (ar >= Ne) ar = Ne - 1;
            int id = GATHER ? row_tok[base + ar] : (base + ar);
            aS[g] = Aglob + (size_t)id * KTOT + lc * 8;
        }
        const size_t bexp = (size_t)e * Ncols * KTOT;
        const _Float16* bS[2];
#pragma unroll
        for (int g = 0; g < 2; g++)
            bS[g] = Bglob + bexp + (size_t)(n0 + w * 32 + g * 16 + srow) * KTOT + lc * 8;

#define STAGE1(S, KOFF) do {                                        \
        glds16(aS[0] + (KOFF), ldsA + (S) * 4096 + 0 * 512);        \
        glds16(aS[1] + (KOFF), ldsA + (S) * 4096 + 1 * 512);        \
        glds16(bS[0] + (KOFF), ldsB + (S) * 4096 + 0 * 512);        \
        glds16(bS[1] + (KOFF), ldsB + (S) * 4096 + 1 * 512);        \
    } while (0)

        f32x4 acc[4][4] = {};
        STAGE1(0, 0);

        for (int j = 0; j < NT; ++j) {
            int slot = j & 1;
            const _Float16* Ab = &As[slot][0][0];
            const _Float16* Bb = &Bs[slot][0][0];
            if (j + 1 < NT) {
                STAGE1(slot ^ 1, (j + 1) * 32);
                asm volatile("s_waitcnt vmcnt(4)" ::: "memory");
            } else {
                asm volatile("s_waitcnt vmcnt(0)" ::: "memory");
            }
            __builtin_amdgcn_s_barrier();

            f16x8 a_[4], b_[4];
#pragma unroll
            for (int ii = 0; ii < 4; ii++)
                a_[ii] = lds_read32(Ab, wr * 64 + ii * 16 + fr, fq);
#pragma unroll
            for (int jj = 0; jj < 4; jj++)
                b_[jj] = lds_read32(Bb, wc * 64 + jj * 16 + fr, fq);
#pragma unroll
            for (int ii = 0; ii < 4; ii++)
#pragma unroll
                for (int jj = 0; jj < 4; jj++)
                    acc[ii][jj] = __builtin_amdgcn_mfma_f32_16x16x32_f16(
                        a_[ii], b_[jj], acc[ii][jj], 0, 0, 0);
            asm volatile("s_waitcnt lgkmcnt(0)" ::: "memory");
            __builtin_amdgcn_s_barrier();
        }
#undef STAGE1

        // ---- epilogue ----
#pragma unroll
        for (int mi = 0; mi < 4; mi++) {
#pragma unroll
            for (int r = 0; r < 4; r++) {
                int row = m0 + wr * 64 + mi * 16 + fq * 4 + r;
                if (row < Ne) {
                    _Float16* dst = Out + (size_t)(base + row) * Ncols + n0 + wc * 64 + fr;
#pragma unroll
                    for (int ni = 0; ni < 4; ni++) {
                        float v = acc[mi][ni][r];
                        if (GELU) v = gelu_tanh(v);
                        dst[ni * 16] = (_Float16)v;
                    }
                }
            }
        }
    }
}

// ====== GEMM2: 256x256 tile, BK=64, 8 waves (wave-tile 128x64), 4-phase counted-vmcnt ======
template<int KTOT, int NX>
__global__ __launch_bounds__(512, 2) void gemm256_kernel(
    const _Float16* __restrict__ Aglob,
    const _Float16* __restrict__ Bglob,
    const int* __restrict__ cnt, const int* __restrict__ offs,
    const int* __restrict__ ttab2,
    const int* __restrict__ nmt,
    int* __restrict__ steal,
    _Float16* __restrict__ Out, int Ncols)
{
    constexpr int NT = KTOT / 64;
    __shared__ __align__(16) _Float16 As[2][256][64];
    __shared__ __align__(16) _Float16 Bs[2][256][64];
    __shared__ int s_it;

    int tid = threadIdx.x;
    int w = tid >> 6, lane = tid & 63;
    int wr = w >> 2, wc = w & 3;
    int fr = lane & 15, fq = lane >> 4;

    int n_items = nmt[1] * NX;
    int chunk = (n_items + 7) >> 3;
    int xcd = blockIdx.x & 7;

    int grow = lane >> 3;
    int lc = (lane & 7) ^ grow;

    _Float16* ldsA = &As[0][0][0] + (w * 32) * 64;
    _Float16* ldsB = &Bs[0][0][0] + (w * 32) * 64;

    for (;;) {
        __syncthreads();
        if (tid == 0) s_it = atomicAdd(&steal[xcd], 1);
        __syncthreads();
        int i = s_it;
        if (i >= chunk) break;
        int it = xcd * chunk + i;
        if (it >= n_items) break;

        int ent = ttab2[it / NX];
        int e = ent >> 16;
        int m0 = (ent & 0xffff) << 8;
        int Ne = cnt[e];
        int base = offs[e];
        int n0 = (it & (NX - 1)) << 8;

        const _Float16* aS[4];
#pragma unroll
        for (int g = 0; g < 4; g++) {
            int ar = m0 + w * 32 + g * 8 + grow; if (ar >= Ne) ar = Ne - 1;
            aS[g] = Aglob + (size_t)(base + ar) * KTOT + lc * 8;
        }
        const size_t bexp = (size_t)e * Ncols * KTOT;
        const _Float16* bS[4];
#pragma unroll
        for (int g = 0; g < 4; g++)
            bS[g] = Bglob + bexp + (size_t)(n0 + w * 32 + g * 8 + grow) * KTOT + lc * 8;

        f32x4 acc[8][4] = {};

#pragma unroll
        for (int g = 0; g < 4; g++) glds16(aS[g], ldsA + g * 512);
#pragma unroll
        for (int g = 0; g < 4; g++) glds16(bS[g], ldsB + g * 512);

        for (int j = 0; j < NT; ++j) {
            int slot = j & 1;
            const _Float16* Ab = &As[slot][0][0];
            const _Float16* Bb = &Bs[slot][0][0];
            _Float16* An = ldsA + (slot ^ 1) * 16384;
            _Float16* Bn = ldsB + (slot ^ 1) * 16384;
            int koff = (j + 1) * 64;
            bool more = (j + 1 < NT);
            if (more) {
                glds16(aS[0] + koff, An + 0 * 512);
                glds16(aS[1] + koff, An + 1 * 512);
                asm volatile("s_waitcnt vmcnt(2)" ::: "memory");
            } else {
                asm volatile("s_waitcnt vmcnt(0)" ::: "memory");
            }
            __builtin_amdgcn_s_barrier();

            f16x8 b_[4];
            {
                f16x8 a_[4];
#pragma unroll
                for (int i2 = 0; i2 < 4; i2++)
                    a_[i2] = lds_read(Ab, wr * 128 + i2 * 16 + fr, fq);
#pragma unroll
                for (int jj = 0; jj < 4; jj++)
                    b_[jj] = lds_read(Bb, wc * 64 + jj * 16 + fr, fq);
                if (more) { glds16(aS[2] + koff, An + 2 * 512); glds16(aS[3] + koff, An + 3 * 512); }
                __builtin_amdgcn_s_barrier();
                asm volatile("s_waitcnt lgkmcnt(0)" ::: "memory");
                __builtin_amdgcn_s_setprio(1);
#pragma unroll
                for (int i2 = 0; i2 < 4; i2++)
#pragma unroll
                    for (int jj = 0; jj < 4; jj++)
                        acc[i2][jj] = __builtin_amdgcn_mfma_f32_16x16x32_f16(
                            a_[i2], b_[jj], acc[i2][jj], 0, 0, 0);
                __builtin_amdgcn_s_setprio(0);
                __builtin_amdgcn_s_barrier();
            }
            {
                f16x8 a_[4];
#pragma unroll
                for (int i2 = 0; i2 < 4; i2++)
                    a_[i2] = lds_read(Ab, wr * 128 + (4 + i2) * 16 + fr, fq);
                if (more) { glds16(bS[0] + koff, Bn + 0 * 512); glds16(bS[1] + koff, Bn + 1 * 512); }
                __builtin_amdgcn_s_barrier();
                asm volatile("s_waitcnt lgkmcnt(0)" ::: "memory");
                __builtin_amdgcn_s_setprio(1);
#pragma unroll
                for (int i2 = 0; i2 < 4; i2++)
#pragma unroll
                    for (int jj = 0; jj < 4; jj++)
                        acc[4 + i2][jj] = __builtin_amdgcn_mfma_f32_16x16x32_f16(
                            a_[i2], b_[jj], acc[4 + i2][jj], 0, 0, 0);
                __builtin_amdgcn_s_setprio(0);
                __builtin_amdgcn_s_barrier();
            }
            {
                f16x8 a_[4];
#pragma unroll
                for (int i2 = 0; i2 < 4; i2++)
                    a_[i2] = lds_read(Ab, wr * 128 + i2 * 16 + fr, 4 + fq);
#pragma unroll
                for (int jj = 0; jj < 4; jj++)
                    b_[jj] = lds_read(Bb, wc * 64 + jj * 16 + fr, 4 + fq);
                if (more) { glds16(bS[2] + koff, Bn + 2 * 512); glds16(bS[3] + koff, Bn + 3 * 512); }
                __builtin_amdgcn_s_barrier();
                asm volatile("s_waitcnt lgkmcnt(0)" ::: "memory");
                __builtin_amdgcn_s_setprio(1);
#pragma unroll
                for (int i2 = 0; i2 < 4; i2++)
#pragma unroll
                    for (int jj = 0; jj < 4; jj++)
                        acc[i2][jj] = __builtin_amdgcn_mfma_f32_16x16x32_f16(
                            a_[i2], b_[jj], acc[i2][jj], 0, 0, 0);
                __builtin_amdgcn_s_setprio(0);
                __builtin_amdgcn_s_barrier();
            }
            {
                f16x8 a_[4];
#pragma unroll
                for (int i2 = 0; i2 < 4; i2++)
                    a_[i2] = lds_read(Ab, wr * 128 + (4 + i2) * 16 + fr, 4 + fq);
                __builtin_amdgcn_s_barrier();
                asm volatile("s_waitcnt lgkmcnt(0)" ::: "memory");
                __builtin_amdgcn_s_setprio(1);
#pragma unroll
                for (int i2 = 0; i2 < 4; i2++)
#pragma unroll
                    for (int jj = 0; jj < 4; jj++)
                        acc[4 + i2][jj] = __builtin_amdgcn_mfma_f32_16x16x32_f16(
                            a_[i2], b_[jj], acc[4 + i2][jj], 0, 0, 0);
                __builtin_amdgcn_s_setprio(0);
                __builtin_amdgcn_s_barrier();
            }
        }

#pragma unroll
        for (int mi = 0; mi < 8; mi++) {
#pragma unroll
            for (int r = 0; r < 4; r++) {
                int row = m0 + wr * 128 + mi * 16 + fq * 4 + r;
                if (row < Ne) {
                    _Float16* dst = Out + (size_t)(base + row) * Ncols + n0 + wc * 64 + fr;
#pragma unroll
                    for (int ni = 0; ni < 4; ni++)
                        dst[ni * 16] = (_Float16)acc[mi][ni][r];
                }
            }
        }
    }
}

// ---------------- combine: out[t] = w0*y[r0] + w1*y[r1] ----------------
__global__ __launch_bounds__(256) void combine_kernel(const _Float16* __restrict__ y,
                                                      const int* __restrict__ tok_row,
                                                      const float* __restrict__ tk_w,
                                                      float* __restrict__ out) {
    int t = blockIdx.x;
    int c = threadIdx.x;
    int r0 = tok_row[2 * t], r1 = tok_row[2 * t + 1];
    float w0 = tk_w[2 * t], w1 = tk_w[2 * t + 1];
    f16x8 a = reinterpret_cast<const f16x8*>(y + (size_t)r0 * HID)[c];
    f16x8 b = reinterpret_cast<const f16x8*>(y + (size_t)r1 * HID)[c];
    float4 o0, o1;
    o0.x = w0 * (float)a[0] + w1 * (float)b[0];
    o0.y = w0 * (float)a[1] + w1 * (float)b[1];
    o0.z = w0 * (float)a[2] + w1 * (float)b[2];
    o0.w = w0 * (float)a[3] + w1 * (float)b[3];
    o1.x = w0 * (float)a[4] + w1 * (float)b[4];
    o1.y = w0 * (float)a[5] + w1 * (float)b[5];
    o1.z = w0 * (float)a[6] + w1 * (float)b[6];
    o1.w = w0 * (float)a[7] + w1 * (float)b[7];
    float4* dst = reinterpret_cast<float4*>(out + (size_t)t * HID + c * 8);
    dst[0] = o0;
    dst[1] = o1;
}

extern "C" void kernel_launch(void* const* d_in, const int* in_sizes, int n_in,
                              void* d_out, int out_size, void* d_ws, size_t ws_size,
                              hipStream_t stream) {
    const float* x  = (const float*)d_in[0];
    const float* gw = (const float*)d_in[1];
    const float* w1 = (const float*)d_in[2];
    const float* w2 = (const float*)d_in[3];
    float* out = (float*)d_out;
    char* ws = (char*)d_ws;

    int*    cnt       = (int*)(ws + 0);
    int*    cursor    = (int*)(ws + 64);
    int*    offs      = (int*)(ws + 128);
    int*    nmt       = (int*)(ws + 256);
    int*    steal     = (int*)(ws + 320);
    int*    ttab      = (int*)(ws + 512);
    int*    ttab2     = (int*)(ws + 2048);
    int*    part_cnt  = (int*)(ws + 4096);
    double* part_sumP = (double*)(ws + 131072);
    int*    row_tok   = (int*)(ws + 262144);
    float*  row_w     = (float*)(ws + 327680);
    int*    tk_idx    = (int*)(ws + 393216);
    float*  tk_w      = (float*)(ws + 458752);
    int*    tok_row   = (int*)(ws + 524288);
    const size_t OFF = 589824;
    _Float16* xh  = (_Float16*)(ws + OFF);
    _Float16* w1t = (_Float16*)(ws + OFF + (1ull << 25));
    _Float16* w2t = (_Float16*)(ws + OFF + (2ull << 25));
    _Float16* hh  = (_Float16*)(ws + OFF + (3ull << 25));
    _Float16* y   = (_Float16*)(ws + OFF);   // aliases xh+w1t (dead after gemm1)

    prep_kernel<<<32768 + GATE_NB, 256, 0, stream>>>(x, gw, w1, w2, xh, w1t, w2t,
                                                     tk_idx, tk_w, part_cnt, part_sumP);
    finalize_kernel<<<1, 256, 0, stream>>>(part_cnt, part_sumP, cnt, offs, cursor,
                                           ttab, ttab2, nmt, steal,
                                           out + (size_t)T_TOKENS * HID);
    scatter_kernel<<<T_TOKENS / 256, 256, 0, stream>>>(tk_idx, tk_w, offs, cursor,
                                                       row_tok, row_w, tok_row);

    gemmf_kernel<true, true, HID, INTERM / 128>
        <<<GEMM1_NB, 256, 0, stream>>>(xh, w1t, cnt, offs, row_tok, ttab, nmt, steal, hh, INTERM);
    gemm256_kernel<INTERM, HID / 256>
        <<<GEMM2_NB, 512, 0, stream>>>(hh, w2t, cnt, offs, ttab2, nmt, steal + 8, y, HID);

    combine_kernel<<<T_TOKENS, 256, 0, stream>>>(y, tok_row, tk_w, out);
}

// Round 12
// 378.231 us; speedup vs baseline: 1.0320x; 1.0320x over previous
//
#include <hip/hip_runtime.h>
#include <hip/hip_fp16.h>
#include <cmath>

#define T_TOKENS 8192
#define HID 2048
#define NEXP 8
#define INTERM 1024
#define GATE_NB 2048
#define MAX_TT 136
#define GEMM1_GRID (8 * 136)    // one block per item, XCD-affine: 8 * chunk_max
#define GEMM2_GRID (8 * 272)

typedef _Float16 f16x8 __attribute__((ext_vector_type(8)));
typedef _Float16 f16x4 __attribute__((ext_vector_type(4)));
typedef float f32x4 __attribute__((ext_vector_type(4)));

static __device__ __forceinline__ float gelu_tanh(float v) {
    return 0.5f * v * (1.0f + tanhf(0.79788456080286535588f * (v + 0.044715f * v * v * v)));
}

static __device__ __forceinline__ void glds16(const void* g, void* l) {
    __builtin_amdgcn_global_load_lds((const __attribute__((address_space(1))) void*)g,
                                     (__attribute__((address_space(3))) void*)l, 16, 0, 0);
}

// 64B-row tiles (BK=32): phys 16B-chunk = chunk ^ ((row>>1)&3)  [R8/R11-verified, 0 conflicts]
static __device__ __forceinline__ f16x8 lds_read32(const _Float16* base, int row, int chunk) {
    int phys = chunk ^ ((row >> 1) & 3);
    return *reinterpret_cast<const f16x8*>(
        reinterpret_cast<const char*>(base) + row * 64 + phys * 16);
}

// ------------- tconv body: fp32 [Z][R][C] -> fp16 [Z][C][R] -------------
static __device__ __forceinline__ void tconv_body(const float* __restrict__ in,
                                                  _Float16* __restrict__ out,
                                                  int R, int C, int bx, int by, int bz) {
    __shared__ float t[32][33];
    int r0 = by * 32, c0 = bx * 32;
    int tid = threadIdx.x;
    int r = tid >> 3, c4 = (tid & 7) * 4;
    const float4 v = *reinterpret_cast<const float4*>(&in[((size_t)bz * R + (r0 + r)) * C + c0 + c4]);
    t[r][c4 + 0] = v.x; t[r][c4 + 1] = v.y; t[r][c4 + 2] = v.z; t[r][c4 + 3] = v.w;
    __syncthreads();
    int oc = tid >> 3;
    int or4 = (tid & 7) * 4;
    f16x4 o;
    o[0] = (_Float16)t[or4 + 0][oc];
    o[1] = (_Float16)t[or4 + 1][oc];
    o[2] = (_Float16)t[or4 + 2][oc];
    o[3] = (_Float16)t[or4 + 3][oc];
    *reinterpret_cast<f16x4*>(&out[((size_t)bz * C + (c0 + oc)) * R + r0 + or4]) = o;
}

// -------- gate body: one wave per token; emits xh = fp16(x) --------
static __device__ __forceinline__ void gate_body(const float* __restrict__ x,
                                                 const float* __restrict__ gw,
                                                 _Float16* __restrict__ xh,
                                                 int* __restrict__ tk_idx, float* __restrict__ tk_w,
                                                 int* __restrict__ part_cnt,
                                                 double* __restrict__ part_sumP, int gid) {
    __shared__ double sds[4][NEXP];
    __shared__ int sci[4][NEXP];
    int w = threadIdx.x >> 6;
    int lane = threadIdx.x & 63;
    int t = gid * 4 + w;

    const float4* xr = (const float4*)(x + (size_t)t * HID);
    _Float16* xo = xh + (size_t)t * HID;
    double acc[NEXP];
#pragma unroll
    for (int e = 0; e < NEXP; e++) acc[e] = 0.0;
#pragma unroll
    for (int i = 0; i < HID / 256; i++) {
        float4 xv = xr[i * 64 + lane];
        f16x4 h;
        h[0] = (_Float16)xv.x; h[1] = (_Float16)xv.y;
        h[2] = (_Float16)xv.z; h[3] = (_Float16)xv.w;
        *reinterpret_cast<f16x4*>(xo + i * 256 + lane * 4) = h;
#pragma unroll
        for (int e = 0; e < NEXP; e++) {
            float4 gv = ((const float4*)(gw + (size_t)e * HID))[i * 64 + lane];
            acc[e] += (double)xv.x * (double)gv.x + (double)xv.y * (double)gv.y
                    + (double)xv.z * (double)gv.z + (double)xv.w * (double)gv.w;
        }
    }
#pragma unroll
    for (int e = 0; e < NEXP; e++) {
#pragma unroll
        for (int off = 32; off > 0; off >>= 1) acc[e] += __shfl_xor(acc[e], off, 64);
    }
    double mx = acc[0];
#pragma unroll
    for (int e = 1; e < NEXP; e++) mx = acc[e] > mx ? acc[e] : mx;
    double ex[NEXP];
    double sum = 0.0;
#pragma unroll
    for (int e = 0; e < NEXP; e++) { ex[e] = exp(acc[e] - mx); sum += ex[e]; }
    int i0 = 0;
#pragma unroll
    for (int e = 1; e < NEXP; e++) if (ex[e] > ex[i0]) i0 = e;
    int i1 = (i0 == 0) ? 1 : 0;
#pragma unroll
    for (int e = 0; e < NEXP; e++) if (e != i0 && ex[e] > ex[i1]) i1 = e;
    double p0 = ex[i0], p1 = ex[i1];
    double t2 = p0 + p1;
    if (lane == 0) {
        tk_idx[2 * t] = i0; tk_idx[2 * t + 1] = i1;
        tk_w[2 * t] = (float)(p0 / t2); tk_w[2 * t + 1] = (float)(p1 / t2);
#pragma unroll
        for (int e = 0; e < NEXP; e++) {
            sds[w][e] = ex[e] / sum;
            sci[w][e] = (e == i0 ? 1 : 0) + (e == i1 ? 1 : 0);
        }
    }
    __syncthreads();
    if (threadIdx.x < NEXP) {
        int e = threadIdx.x;
        part_sumP[e * GATE_NB + gid] = sds[0][e] + sds[1][e] + sds[2][e] + sds[3][e];
        part_cnt[e * GATE_NB + gid]  = sci[0][e] + sci[1][e] + sci[2][e] + sci[3][e];
    }
}

// -------- fused prep: [0,16384) tconv w1, [16384,32768) tconv w2, [32768,34816) gate --------
__global__ __launch_bounds__(256) void prep_kernel(const float* __restrict__ x,
                                                   const float* __restrict__ gw,
                                                   const float* __restrict__ w1,
                                                   const float* __restrict__ w2,
                                                   _Float16* __restrict__ xh,
                                                   _Float16* __restrict__ w1t,
                                                   _Float16* __restrict__ w2t,
                                                   int* __restrict__ tk_idx, float* __restrict__ tk_w,
                                                   int* __restrict__ part_cnt,
                                                   double* __restrict__ part_sumP) {
    int bid = blockIdx.x;
    if (bid < 16384) {
        int bx = bid & 31, by = (bid >> 5) & 63, bz = bid >> 11;
        tconv_body(w1, w1t, HID, INTERM, bx, by, bz);
    } else if (bid < 32768) {
        int r = bid - 16384;
        int bx = r & 63, by = (r >> 6) & 31, bz = r >> 11;
        tconv_body(w2, w2t, INTERM, HID, bx, by, bz);
    } else {
        gate_body(x, gw, xh, tk_idx, tk_w, part_cnt, part_sumP, bid - 32768);
    }
}

// ------- reduce partials, offsets, aux, cursor, tile table (BM=128) -------
__global__ __launch_bounds__(256) void finalize_kernel(const int* __restrict__ part_cnt,
                                                       const double* __restrict__ part_sumP,
                                                       int* __restrict__ cnt, int* __restrict__ offs,
                                                       int* __restrict__ cursor,
                                                       int* __restrict__ ttab,
                                                       int* __restrict__ nmt,
                                                       float* __restrict__ aux_out) {
    __shared__ double swv[4];
    __shared__ int cwv[4];
    __shared__ double sE[NEXP];
    __shared__ int cE[NEXP];
    int w = threadIdx.x >> 6;
    int lane = threadIdx.x & 63;
    for (int e = 0; e < NEXP; e++) {
        double s = 0.0; int c = 0;
        for (int j = threadIdx.x; j < GATE_NB; j += 256) {
            s += part_sumP[e * GATE_NB + j];
            c += part_cnt[e * GATE_NB + j];
        }
#pragma unroll
        for (int off = 32; off > 0; off >>= 1) {
            s += __shfl_xor(s, off, 64);
            c += __shfl_xor(c, off, 64);
        }
        if (lane == 0) { swv[w] = s; cwv[w] = c; }
        __syncthreads();
        if (threadIdx.x == 0) {
            sE[e] = swv[0] + swv[1] + swv[2] + swv[3];
            cE[e] = cwv[0] + cwv[1] + cwv[2] + cwv[3];
        }
        __syncthreads();
    }
    if (threadIdx.x == 0) {
        int off = 0;
        double aux = 0.0;
        int idx = 0;
#pragma unroll
        for (int e = 0; e < NEXP; e++) {
            cnt[e] = cE[e];
            offs[e] = off;
            off += cE[e];
            cursor[e] = 0;
            aux += ((double)cE[e] / (double)T_TOKENS) * (sE[e] / (double)T_TOKENS);
            int mt = (cE[e] + 127) >> 7;
            for (int m = 0; m < mt; m++) ttab[idx++] = (e << 16) | m;
        }
        nmt[0] = idx;
        for (; idx < MAX_TT; idx++) ttab[idx] = -1;
        aux_out[0] = (float)(0.01 * (double)NEXP * aux);
    }
}

// ------- build per-expert row lists + inverse map (wave-aggregated atomics) -------
__global__ void scatter_kernel(const int* __restrict__ tk_idx, const float* __restrict__ tk_w,
                               const int* __restrict__ offs, int* __restrict__ cursor,
                               int* __restrict__ row_tok, float* __restrict__ row_w,
                               int* __restrict__ tok_row) {
    int t = blockIdx.x * blockDim.x + threadIdx.x;
    int lane = threadIdx.x & 63;
    unsigned long long below = (lane == 0) ? 0ull : ((~0ull) >> (64 - lane));
    for (int k = 0; k < 2; k++) {
        int e = tk_idx[2 * t + k];
        float wv = tk_w[2 * t + k];
        int pos = 0;
#pragma unroll
        for (int ee = 0; ee < NEXP; ee++) {
            unsigned long long m = __ballot(e == ee);
            if (e == ee) {
                int rank = (int)__popcll(m & below);
                int leader = (int)__ffsll((unsigned long long)m) - 1;
                int b = 0;
                if (lane == leader) b = atomicAdd(&cursor[ee], (int)__popcll(m));
                b = __shfl(b, leader, 64);
                pos = b + rank;
            }
        }
        int r = offs[e] + pos;
        row_tok[r] = t;
        row_w[r] = wv;
        tok_row[2 * t + k] = r;
    }
}

// ====== Grouped GEMM: 128x128 tile, BK=32, 4 waves, 32KB LDS (4 blocks/CU) ======
// One item per block, XCD-affine mapping: xcd = bid&7, i = bid>>3,
// item = xcd*chunk + i  (chunk = ceil(n_items/8)). No persistence, no steal —
// HW refills freed CU slots from the queue, so the makespan tail is ~1 item.
template<bool GATHER, bool GELU, int KTOT, int NX>
__global__ __launch_bounds__(256, 4) void gemmf_kernel(
    const _Float16* __restrict__ Aglob,
    const _Float16* __restrict__ Bglob,
    const int* __restrict__ cnt, const int* __restrict__ offs,
    const int* __restrict__ row_tok,
    const int* __restrict__ ttab,
    const int* __restrict__ nmt,
    _Float16* __restrict__ Out, int Ncols)
{
    constexpr int NT = KTOT / 32;
    __shared__ __align__(16) _Float16 As[2][128][32];   // 16KB
    __shared__ __align__(16) _Float16 Bs[2][128][32];   // 16KB

    int n_items = nmt[0] * NX;
    int chunk = (n_items + 7) >> 3;
    int xcd = blockIdx.x & 7;
    int i = blockIdx.x >> 3;
    if (i >= chunk) return;
    int it = xcd * chunk + i;
    if (it >= n_items) return;

    int tid = threadIdx.x;
    int w = tid >> 6, lane = tid & 63;
    int wr = w >> 1, wc = w & 1;          // 2x2 wave grid, wave-tile 64x64
    int fr = lane & 15, fq = lane >> 4;

    int srow = lane >> 2;                      // 0..15 row within one glds (64B rows)
    int lc = (lane & 3) ^ ((lane >> 3) & 3);   // pre-swizzled 16B chunk

    _Float16* ldsA = &As[0][0][0] + w * 1024;  // wave stages A rows [32w,32w+32)
    _Float16* ldsB = &Bs[0][0][0] + w * 1024;

    int ent = ttab[it / NX];
    int e = ent >> 16;
    int m0 = (ent & 0xffff) << 7;
    int Ne = cnt[e];
    int base = offs[e];
    int n0 = (it & (NX - 1)) << 7;

    const _Float16* aS[2];
#pragma unroll
    for (int g = 0; g < 2; g++) {
        int ar = m0 + w * 32 + g * 16 + srow; if (ar >= Ne) ar = Ne - 1;
        int id = GATHER ? row_tok[base + ar] : (base + ar);
        aS[g] = Aglob + (size_t)id * KTOT + lc * 8;
    }
    const size_t bexp = (size_t)e * Ncols * KTOT;
    const _Float16* bS[2];
#pragma unroll
    for (int g = 0; g < 2; g++)
        bS[g] = Bglob + bexp + (size_t)(n0 + w * 32 + g * 16 + srow) * KTOT + lc * 8;

#define STAGE1(S, KOFF) do {                                        \
        glds16(aS[0] + (KOFF), ldsA + (S) * 4096 + 0 * 512);        \
        glds16(aS[1] + (KOFF), ldsA + (S) * 4096 + 1 * 512);        \
        glds16(bS[0] + (KOFF), ldsB + (S) * 4096 + 0 * 512);        \
        glds16(bS[1] + (KOFF), ldsB + (S) * 4096 + 1 * 512);        \
    } while (0)

    f32x4 acc[4][4] = {};
    STAGE1(0, 0);

    for (int j = 0; j < NT; ++j) {
        int slot = j & 1;
        const _Float16* Ab = &As[slot][0][0];
        const _Float16* Bb = &Bs[slot][0][0];
        if (j + 1 < NT) {
            STAGE1(slot ^ 1, (j + 1) * 32);
            asm volatile("s_waitcnt vmcnt(4)" ::: "memory");
        } else {
            asm volatile("s_waitcnt vmcnt(0)" ::: "memory");
        }
        __builtin_amdgcn_s_barrier();

        f16x8 a_[4], b_[4];
#pragma unroll
        for (int ii = 0; ii < 4; ii++)
            a_[ii] = lds_read32(Ab, wr * 64 + ii * 16 + fr, fq);
#pragma unroll
        for (int jj = 0; jj < 4; jj++)
            b_[jj] = lds_read32(Bb, wc * 64 + jj * 16 + fr, fq);
#pragma unroll
        for (int ii = 0; ii < 4; ii++)
#pragma unroll
            for (int jj = 0; jj < 4; jj++)
                acc[ii][jj] = __builtin_amdgcn_mfma_f32_16x16x32_f16(
                    a_[ii], b_[jj], acc[ii][jj], 0, 0, 0);
        asm volatile("s_waitcnt lgkmcnt(0)" ::: "memory");
        __builtin_amdgcn_s_barrier();
    }
#undef STAGE1

    // ---- epilogue ----
#pragma unroll
    for (int mi = 0; mi < 4; mi++) {
#pragma unroll
        for (int r = 0; r < 4; r++) {
            int row = m0 + wr * 64 + mi * 16 + fq * 4 + r;
            if (row < Ne) {
                _Float16* dst = Out + (size_t)(base + row) * Ncols + n0 + wc * 64 + fr;
#pragma unroll
                for (int ni = 0; ni < 4; ni++) {
                    float v = acc[mi][ni][r];
                    if (GELU) v = gelu_tanh(v);
                    dst[ni * 16] = (_Float16)v;
                }
            }
        }
    }
}

// ---------------- combine: out[t] = w0*y[r0] + w1*y[r1] ----------------
__global__ __launch_bounds__(256) void combine_kernel(const _Float16* __restrict__ y,
                                                      const int* __restrict__ tok_row,
                                                      const float* __restrict__ tk_w,
                                                      float* __restrict__ out) {
    int t = blockIdx.x;
    int c = threadIdx.x;
    int r0 = tok_row[2 * t], r1 = tok_row[2 * t + 1];
    float w0 = tk_w[2 * t], w1 = tk_w[2 * t + 1];
    f16x8 a = reinterpret_cast<const f16x8*>(y + (size_t)r0 * HID)[c];
    f16x8 b = reinterpret_cast<const f16x8*>(y + (size_t)r1 * HID)[c];
    float4 o0, o1;
    o0.x = w0 * (float)a[0] + w1 * (float)b[0];
    o0.y = w0 * (float)a[1] + w1 * (float)b[1];
    o0.z = w0 * (float)a[2] + w1 * (float)b[2];
    o0.w = w0 * (float)a[3] + w1 * (float)b[3];
    o1.x = w0 * (float)a[4] + w1 * (float)b[4];
    o1.y = w0 * (float)a[5] + w1 * (float)b[5];
    o1.z = w0 * (float)a[6] + w1 * (float)b[6];
    o1.w = w0 * (float)a[7] + w1 * (float)b[7];
    float4* dst = reinterpret_cast<float4*>(out + (size_t)t * HID + c * 8);
    dst[0] = o0;
    dst[1] = o1;
}

extern "C" void kernel_launch(void* const* d_in, const int* in_sizes, int n_in,
                              void* d_out, int out_size, void* d_ws, size_t ws_size,
                              hipStream_t stream) {
    const float* x  = (const float*)d_in[0];
    const float* gw = (const float*)d_in[1];
    const float* w1 = (const float*)d_in[2];
    const float* w2 = (const float*)d_in[3];
    float* out = (float*)d_out;
    char* ws = (char*)d_ws;

    int*    cnt       = (int*)(ws + 0);
    int*    cursor    = (int*)(ws + 64);
    int*    offs      = (int*)(ws + 128);
    int*    nmt       = (int*)(ws + 256);
    int*    ttab      = (int*)(ws + 512);
    int*    part_cnt  = (int*)(ws + 4096);
    double* part_sumP = (double*)(ws + 131072);
    int*    row_tok   = (int*)(ws + 262144);
    float*  row_w     = (float*)(ws + 327680);
    int*    tk_idx    = (int*)(ws + 393216);
    float*  tk_w      = (float*)(ws + 458752);
    int*    tok_row   = (int*)(ws + 524288);
    const size_t OFF = 589824;
    _Float16* xh  = (_Float16*)(ws + OFF);
    _Float16* w1t = (_Float16*)(ws + OFF + (1ull << 25));
    _Float16* w2t = (_Float16*)(ws + OFF + (2ull << 25));
    _Float16* hh  = (_Float16*)(ws + OFF + (3ull << 25));
    _Float16* y   = (_Float16*)(ws + OFF);   // aliases xh+w1t (dead after gemm1)

    prep_kernel<<<32768 + GATE_NB, 256, 0, stream>>>(x, gw, w1, w2, xh, w1t, w2t,
                                                     tk_idx, tk_w, part_cnt, part_sumP);
    finalize_kernel<<<1, 256, 0, stream>>>(part_cnt, part_sumP, cnt, offs, cursor,
                                           ttab, nmt, out + (size_t)T_TOKENS * HID);
    scatter_kernel<<<T_TOKENS / 256, 256, 0, stream>>>(tk_idx, tk_w, offs, cursor,
                                                       row_tok, row_w, tok_row);

    gemmf_kernel<true, true, HID, INTERM / 128>
        <<<GEMM1_GRID, 256, 0, stream>>>(xh, w1t, cnt, offs, row_tok, ttab, nmt, hh, INTERM);
    gemmf_kernel<false, false, INTERM, HID / 128>
        <<<GEMM2_GRID, 256, 0, stream>>>(hh, w2t, cnt, offs, row_tok, ttab, nmt, y, HID);

    combine_kernel<<<T_TOKENS, 256, 0, stream>>>(y, tok_row, tk_w, out);
}

// Round 13
// 372.868 us; speedup vs baseline: 1.0469x; 1.0144x over previous
//
#include <hip/hip_runtime.h>
#include <hip/hip_fp16.h>
#include <cmath>

#define T_TOKENS 8192
#define HID 2048
#define NEXP 8
#define INTERM 1024
#define GATE_NB 2048
#define MAX_TT 136
#define GEMM1_GRID (8 * 136)    // one block per item, XCD-affine
#define W2_BLOCKS 16384         // w2 tconv blocks appended to gemm1 dispatch
#define GEMM2_GRID (8 * 272)

typedef _Float16 f16x8 __attribute__((ext_vector_type(8)));
typedef _Float16 f16x4 __attribute__((ext_vector_type(4)));
typedef float f32x4 __attribute__((ext_vector_type(4)));

static __device__ __forceinline__ float gelu_tanh(float v) {
    return 0.5f * v * (1.0f + tanhf(0.79788456080286535588f * (v + 0.044715f * v * v * v)));
}

static __device__ __forceinline__ void glds16(const void* g, void* l) {
    __builtin_amdgcn_global_load_lds((const __attribute__((address_space(1))) void*)g,
                                     (__attribute__((address_space(3))) void*)l, 16, 0, 0);
}

// 64B-row tiles (BK=32): phys 16B-chunk = chunk ^ ((row>>1)&3)  [verified, 0 conflicts]
static __device__ __forceinline__ f16x8 lds_read32(const _Float16* base, int row, int chunk) {
    int phys = chunk ^ ((row >> 1) & 3);
    return *reinterpret_cast<const f16x8*>(
        reinterpret_cast<const char*>(base) + row * 64 + phys * 16);
}

// ------------- tconv body: fp32 [Z][R][C] -> fp16 [Z][C][R] (shared buf passed in) -------------
static __device__ __forceinline__ void tconv_body(const float* __restrict__ in,
                                                  _Float16* __restrict__ out,
                                                  int R, int C, int bx, int by, int bz,
                                                  float* __restrict__ t /* [32*33] */) {
    int r0 = by * 32, c0 = bx * 32;
    int tid = threadIdx.x;
    int r = tid >> 3, c4 = (tid & 7) * 4;
    const float4 v = *reinterpret_cast<const float4*>(&in[((size_t)bz * R + (r0 + r)) * C + c0 + c4]);
    t[r * 33 + c4 + 0] = v.x; t[r * 33 + c4 + 1] = v.y;
    t[r * 33 + c4 + 2] = v.z; t[r * 33 + c4 + 3] = v.w;
    __syncthreads();
    int oc = tid >> 3;
    int or4 = (tid & 7) * 4;
    f16x4 o;
    o[0] = (_Float16)t[(or4 + 0) * 33 + oc];
    o[1] = (_Float16)t[(or4 + 1) * 33 + oc];
    o[2] = (_Float16)t[(or4 + 2) * 33 + oc];
    o[3] = (_Float16)t[(or4 + 3) * 33 + oc];
    *reinterpret_cast<f16x4*>(&out[((size_t)bz * C + (c0 + oc)) * R + r0 + or4]) = o;
}

// -------- gate body: one wave per token; emits xh = fp16(x) --------
static __device__ __forceinline__ void gate_body(const float* __restrict__ x,
                                                 const float* __restrict__ gw,
                                                 _Float16* __restrict__ xh,
                                                 int* __restrict__ tk_idx, float* __restrict__ tk_w,
                                                 int* __restrict__ part_cnt,
                                                 double* __restrict__ part_sumP, int gid) {
    __shared__ double sds[4][NEXP];
    __shared__ int sci[4][NEXP];
    int w = threadIdx.x >> 6;
    int lane = threadIdx.x & 63;
    int t = gid * 4 + w;

    const float4* xr = (const float4*)(x + (size_t)t * HID);
    _Float16* xo = xh + (size_t)t * HID;
    double acc[NEXP];
#pragma unroll
    for (int e = 0; e < NEXP; e++) acc[e] = 0.0;
#pragma unroll
    for (int i = 0; i < HID / 256; i++) {
        float4 xv = xr[i * 64 + lane];
        f16x4 h;
        h[0] = (_Float16)xv.x; h[1] = (_Float16)xv.y;
        h[2] = (_Float16)xv.z; h[3] = (_Float16)xv.w;
        *reinterpret_cast<f16x4*>(xo + i * 256 + lane * 4) = h;
#pragma unroll
        for (int e = 0; e < NEXP; e++) {
            float4 gv = ((const float4*)(gw + (size_t)e * HID))[i * 64 + lane];
            acc[e] += (double)xv.x * (double)gv.x + (double)xv.y * (double)gv.y
                    + (double)xv.z * (double)gv.z + (double)xv.w * (double)gv.w;
        }
    }
#pragma unroll
    for (int e = 0; e < NEXP; e++) {
#pragma unroll
        for (int off = 32; off > 0; off >>= 1) acc[e] += __shfl_xor(acc[e], off, 64);
    }
    double mx = acc[0];
#pragma unroll
    for (int e = 1; e < NEXP; e++) mx = acc[e] > mx ? acc[e] : mx;
    double ex[NEXP];
    double sum = 0.0;
#pragma unroll
    for (int e = 0; e < NEXP; e++) { ex[e] = exp(acc[e] - mx); sum += ex[e]; }
    int i0 = 0;
#pragma unroll
    for (int e = 1; e < NEXP; e++) if (ex[e] > ex[i0]) i0 = e;
    int i1 = (i0 == 0) ? 1 : 0;
#pragma unroll
    for (int e = 0; e < NEXP; e++) if (e != i0 && ex[e] > ex[i1]) i1 = e;
    double p0 = ex[i0], p1 = ex[i1];
    double t2 = p0 + p1;
    if (lane == 0) {
        tk_idx[2 * t] = i0; tk_idx[2 * t + 1] = i1;
        tk_w[2 * t] = (float)(p0 / t2); tk_w[2 * t + 1] = (float)(p1 / t2);
#pragma unroll
        for (int e = 0; e < NEXP; e++) {
            sds[w][e] = ex[e] / sum;
            sci[w][e] = (e == i0 ? 1 : 0) + (e == i1 ? 1 : 0);
        }
    }
    __syncthreads();
    if (threadIdx.x < NEXP) {
        int e = threadIdx.x;
        part_sumP[e * GATE_NB + gid] = sds[0][e] + sds[1][e] + sds[2][e] + sds[3][e];
        part_cnt[e * GATE_NB + gid]  = sci[0][e] + sci[1][e] + sci[2][e] + sci[3][e];
    }
}

// -------- prep: [0,16384) tconv w1, [16384,18432) gate --------
__global__ __launch_bounds__(256) void prep_kernel(const float* __restrict__ x,
                                                   const float* __restrict__ gw,
                                                   const float* __restrict__ w1,
                                                   _Float16* __restrict__ xh,
                                                   _Float16* __restrict__ w1t,
                                                   int* __restrict__ tk_idx, float* __restrict__ tk_w,
                                                   int* __restrict__ part_cnt,
                                                   double* __restrict__ part_sumP) {
    __shared__ float tsh[32 * 33];
    int bid = blockIdx.x;
    if (bid < 16384) {
        int bx = bid & 31, by = (bid >> 5) & 63, bz = bid >> 11;
        tconv_body(w1, w1t, HID, INTERM, bx, by, bz, tsh);
    } else {
        gate_body(x, gw, xh, tk_idx, tk_w, part_cnt, part_sumP, bid - 16384);
    }
}

// ------- reduce partials, offsets, aux, cursor, tile table (BM=128) -------
__global__ __launch_bounds__(256) void finalize_kernel(const int* __restrict__ part_cnt,
                                                       const double* __restrict__ part_sumP,
                                                       int* __restrict__ cnt, int* __restrict__ offs,
                                                       int* __restrict__ cursor,
                                                       int* __restrict__ ttab,
                                                       int* __restrict__ nmt,
                                                       float* __restrict__ aux_out) {
    __shared__ double swv[4];
    __shared__ int cwv[4];
    __shared__ double sE[NEXP];
    __shared__ int cE[NEXP];
    int w = threadIdx.x >> 6;
    int lane = threadIdx.x & 63;
    for (int e = 0; e < NEXP; e++) {
        double s = 0.0; int c = 0;
        for (int j = threadIdx.x; j < GATE_NB; j += 256) {
            s += part_sumP[e * GATE_NB + j];
            c += part_cnt[e * GATE_NB + j];
        }
#pragma unroll
        for (int off = 32; off > 0; off >>= 1) {
            s += __shfl_xor(s, off, 64);
            c += __shfl_xor(c, off, 64);
        }
        if (lane == 0) { swv[w] = s; cwv[w] = c; }
        __syncthreads();
        if (threadIdx.x == 0) {
            sE[e] = swv[0] + swv[1] + swv[2] + swv[3];
            cE[e] = cwv[0] + cwv[1] + cwv[2] + cwv[3];
        }
        __syncthreads();
    }
    if (threadIdx.x == 0) {
        int off = 0;
        double aux = 0.0;
        int idx = 0;
#pragma unroll
        for (int e = 0; e < NEXP; e++) {
            cnt[e] = cE[e];
            offs[e] = off;
            off += cE[e];
            cursor[e] = 0;
            aux += ((double)cE[e] / (double)T_TOKENS) * (sE[e] / (double)T_TOKENS);
            int mt = (cE[e] + 127) >> 7;
            for (int m = 0; m < mt; m++) ttab[idx++] = (e << 16) | m;
        }
        nmt[0] = idx;
        for (; idx < MAX_TT; idx++) ttab[idx] = -1;
        aux_out[0] = (float)(0.01 * (double)NEXP * aux);
    }
}

// ------- build per-expert row lists + inverse map (wave-aggregated atomics) -------
__global__ void scatter_kernel(const int* __restrict__ tk_idx, const float* __restrict__ tk_w,
                               const int* __restrict__ offs, int* __restrict__ cursor,
                               int* __restrict__ row_tok, float* __restrict__ row_w,
                               int* __restrict__ tok_row) {
    int t = blockIdx.x * blockDim.x + threadIdx.x;
    int lane = threadIdx.x & 63;
    unsigned long long below = (lane == 0) ? 0ull : ((~0ull) >> (64 - lane));
    for (int k = 0; k < 2; k++) {
        int e = tk_idx[2 * t + k];
        float wv = tk_w[2 * t + k];
        int pos = 0;
#pragma unroll
        for (int ee = 0; ee < NEXP; ee++) {
            unsigned long long m = __ballot(e == ee);
            if (e == ee) {
                int rank = (int)__popcll(m & below);
                int leader = (int)__ffsll((unsigned long long)m) - 1;
                int b = 0;
                if (lane == leader) b = atomicAdd(&cursor[ee], (int)__popcll(m));
                b = __shfl(b, leader, 64);
                pos = b + rank;
            }
        }
        int r = offs[e] + pos;
        row_tok[r] = t;
        row_w[r] = wv;
        tok_row[2 * t + k] = r;
    }
}

// ====== GEMM1 (R12 engine, counted-vmcnt dbuf) + fused w2-tconv blocks ======
// Blocks [0, GEMM1_GRID): one GEMM item each (XCD-affine).
// Blocks [GEMM1_GRID, +W2_BLOCKS): w2 fp32->fp16 transpose (rides gemm1's idle HBM).
template<bool GATHER, bool GELU, int KTOT, int NX, bool FUSE>
__global__ __launch_bounds__(256, 4) void gemmf_kernel(
    const _Float16* __restrict__ Aglob,
    const _Float16* __restrict__ Bglob,
    const int* __restrict__ cnt, const int* __restrict__ offs,
    const int* __restrict__ row_tok,
    const int* __restrict__ ttab,
    const int* __restrict__ nmt,
    _Float16* __restrict__ Out, int Ncols,
    const float* __restrict__ w2in, _Float16* __restrict__ w2out)
{
    constexpr int NT = KTOT / 32;
    __shared__ __align__(16) _Float16 As[2][128][32];   // 16KB
    __shared__ __align__(16) _Float16 Bs[2][128][32];   // 16KB

    if (FUSE && blockIdx.x >= GEMM1_GRID) {
        int b = blockIdx.x - GEMM1_GRID;
        int bx = b & 63, by = (b >> 6) & 31, bz = b >> 11;   // w2: R=INTERM, C=HID
        tconv_body(w2in, w2out, INTERM, HID, bx, by, bz,
                   reinterpret_cast<float*>(&As[0][0][0]));
        return;
    }

    int n_items = nmt[0] * NX;
    int chunk = (n_items + 7) >> 3;
    int xcd = blockIdx.x & 7;
    int i = blockIdx.x >> 3;
    if (i >= chunk) return;
    int it = xcd * chunk + i;
    if (it >= n_items) return;

    int tid = threadIdx.x;
    int w = tid >> 6, lane = tid & 63;
    int wr = w >> 1, wc = w & 1;          // 2x2 wave grid, wave-tile 64x64
    int fr = lane & 15, fq = lane >> 4;

    int srow = lane >> 2;                      // 0..15 row within one glds (64B rows)
    int lc = (lane & 3) ^ ((lane >> 3) & 3);   // pre-swizzled 16B chunk

    _Float16* ldsA = &As[0][0][0] + w * 1024;  // wave stages A rows [32w,32w+32)
    _Float16* ldsB = &Bs[0][0][0] + w * 1024;

    int ent = ttab[it / NX];
    int e = ent >> 16;
    int m0 = (ent & 0xffff) << 7;
    int Ne = cnt[e];
    int base = offs[e];
    int n0 = (it & (NX - 1)) << 7;

    const _Float16* aS[2];
#pragma unroll
    for (int g = 0; g < 2; g++) {
        int ar = m0 + w * 32 + g * 16 + srow; if (ar >= Ne) ar = Ne - 1;
        int id = GATHER ? row_tok[base + ar] : (base + ar);
        aS[g] = Aglob + (size_t)id * KTOT + lc * 8;
    }
    const size_t bexp = (size_t)e * Ncols * KTOT;
    const _Float16* bS[2];
#pragma unroll
    for (int g = 0; g < 2; g++)
        bS[g] = Bglob + bexp + (size_t)(n0 + w * 32 + g * 16 + srow) * KTOT + lc * 8;

#define STAGE1(S, KOFF) do {                                        \
        glds16(aS[0] + (KOFF), ldsA + (S) * 4096 + 0 * 512);        \
        glds16(aS[1] + (KOFF), ldsA + (S) * 4096 + 1 * 512);        \
        glds16(bS[0] + (KOFF), ldsB + (S) * 4096 + 0 * 512);        \
        glds16(bS[1] + (KOFF), ldsB + (S) * 4096 + 1 * 512);        \
    } while (0)

    f32x4 acc[4][4] = {};
    STAGE1(0, 0);

    for (int j = 0; j < NT; ++j) {
        int slot = j & 1;
        const _Float16* Ab = &As[slot][0][0];
        const _Float16* Bb = &Bs[slot][0][0];
        if (j + 1 < NT) {
            STAGE1(slot ^ 1, (j + 1) * 32);
            asm volatile("s_waitcnt vmcnt(4)" ::: "memory");
        } else {
            asm volatile("s_waitcnt vmcnt(0)" ::: "memory");
        }
        __builtin_amdgcn_s_barrier();

        f16x8 a_[4], b_[4];
#pragma unroll
        for (int ii = 0; ii < 4; ii++)
            a_[ii] = lds_read32(Ab, wr * 64 + ii * 16 + fr, fq);
#pragma unroll
        for (int jj = 0; jj < 4; jj++)
            b_[jj] = lds_read32(Bb, wc * 64 + jj * 16 + fr, fq);
#pragma unroll
        for (int ii = 0; ii < 4; ii++)
#pragma unroll
            for (int jj = 0; jj < 4; jj++)
                acc[ii][jj] = __builtin_amdgcn_mfma_f32_16x16x32_f16(
                    a_[ii], b_[jj], acc[ii][jj], 0, 0, 0);
        asm volatile("s_waitcnt lgkmcnt(0)" ::: "memory");
        __builtin_amdgcn_s_barrier();
    }
#undef STAGE1

#pragma unroll
    for (int mi = 0; mi < 4; mi++) {
#pragma unroll
        for (int r = 0; r < 4; r++) {
            int row = m0 + wr * 64 + mi * 16 + fq * 4 + r;
            if (row < Ne) {
                _Float16* dst = Out + (size_t)(base + row) * Ncols + n0 + wc * 64 + fr;
#pragma unroll
                for (int ni = 0; ni < 4; ni++) {
                    float v = acc[mi][ni][r];
                    if (GELU) v = gelu_tanh(v);
                    dst[ni * 16] = (_Float16)v;
                }
            }
        }
    }
}

// ====== GEMM2 engine A/B: m97-exact single-buffer, syncthreads-only, no asm ======
// STAGE -> __syncthreads (full drain) -> 8 ds_read + 16 MFMA -> __syncthreads.
// Per-block stalls are covered by 3 co-resident blocks (m114 cross-block overlap).
template<int KTOT, int NX>
__global__ __launch_bounds__(256, 4) void gemms_kernel(
    const _Float16* __restrict__ Aglob,
    const _Float16* __restrict__ Bglob,
    const int* __restrict__ cnt, const int* __restrict__ offs,
    const int* __restrict__ ttab,
    const int* __restrict__ nmt,
    _Float16* __restrict__ Out, int Ncols)
{
    constexpr int NT = KTOT / 32;
    __shared__ __align__(16) _Float16 As[128][32];   // 8KB
    __shared__ __align__(16) _Float16 Bs[128][32];   // 8KB

    int n_items = nmt[0] * NX;
    int chunk = (n_items + 7) >> 3;
    int xcd = blockIdx.x & 7;
    int i = blockIdx.x >> 3;
    if (i >= chunk) return;
    int it = xcd * chunk + i;
    if (it >= n_items) return;

    int tid = threadIdx.x;
    int w = tid >> 6, lane = tid & 63;
    int wr = w >> 1, wc = w & 1;
    int fr = lane & 15, fq = lane >> 4;

    int srow = lane >> 2;
    int lc = (lane & 3) ^ ((lane >> 3) & 3);

    _Float16* ldsA = &As[0][0] + w * 1024;
    _Float16* ldsB = &Bs[0][0] + w * 1024;

    int ent = ttab[it / NX];
    int e = ent >> 16;
    int m0 = (ent & 0xffff) << 7;
    int Ne = cnt[e];
    int base = offs[e];
    int n0 = (it & (NX - 1)) << 7;

    const _Float16* aS[2];
#pragma unroll
    for (int g = 0; g < 2; g++) {
        int ar = m0 + w * 32 + g * 16 + srow; if (ar >= Ne) ar = Ne - 1;
        aS[g] = Aglob + (size_t)(base + ar) * KTOT + lc * 8;
    }
    const size_t bexp = (size_t)e * Ncols * KTOT;
    const _Float16* bS[2];
#pragma unroll
    for (int g = 0; g < 2; g++)
        bS[g] = Bglob + bexp + (size_t)(n0 + w * 32 + g * 16 + srow) * KTOT + lc * 8;

    f32x4 acc[4][4] = {};

    for (int j = 0; j < NT; ++j) {
        int koff = j * 32;
        glds16(aS[0] + koff, ldsA + 0 * 512);
        glds16(aS[1] + koff, ldsA + 1 * 512);
        glds16(bS[0] + koff, ldsB + 0 * 512);
        glds16(bS[1] + koff, ldsB + 1 * 512);
        __syncthreads();                    // drains vmcnt; compiler-managed

        f16x8 a_[4], b_[4];
#pragma unroll
        for (int ii = 0; ii < 4; ii++)
            a_[ii] = lds_read32(&As[0][0], wr * 64 + ii * 16 + fr, fq);
#pragma unroll
        for (int jj = 0; jj < 4; jj++)
            b_[jj] = lds_read32(&Bs[0][0], wc * 64 + jj * 16 + fr, fq);
#pragma unroll
        for (int ii = 0; ii < 4; ii++)
#pragma unroll
            for (int jj = 0; jj < 4; jj++)
                acc[ii][jj] = __builtin_amdgcn_mfma_f32_16x16x32_f16(
                    a_[ii], b_[jj], acc[ii][jj], 0, 0, 0);
        __syncthreads();                    // protect buffer reuse
    }

#pragma unroll
    for (int mi = 0; mi < 4; mi++) {
#pragma unroll
        for (int r = 0; r < 4; r++) {
            int row = m0 + wr * 64 + mi * 16 + fq * 4 + r;
            if (row < Ne) {
                _Float16* dst = Out + (size_t)(base + row) * Ncols + n0 + wc * 64 + fr;
#pragma unroll
                for (int ni = 0; ni < 4; ni++)
                    dst[ni * 16] = (_Float16)acc[mi][ni][r];
            }
        }
    }
}

// ---------------- combine: out[t] = w0*y[r0] + w1*y[r1] ----------------
__global__ __launch_bounds__(256) void combine_kernel(const _Float16* __restrict__ y,
                                                      const int* __restrict__ tok_row,
                                                      const float* __restrict__ tk_w,
                                                      float* __restrict__ out) {
    int t = blockIdx.x;
    int c = threadIdx.x;
    int r0 = tok_row[2 * t], r1 = tok_row[2 * t + 1];
    float w0 = tk_w[2 * t], w1 = tk_w[2 * t + 1];
    f16x8 a = reinterpret_cast<const f16x8*>(y + (size_t)r0 * HID)[c];
    f16x8 b = reinterpret_cast<const f16x8*>(y + (size_t)r1 * HID)[c];
    float4 o0, o1;
    o0.x = w0 * (float)a[0] + w1 * (float)b[0];
    o0.y = w0 * (float)a[1] + w1 * (float)b[1];
    o0.z = w0 * (float)a[2] + w1 * (float)b[2];
    o0.w = w0 * (float)a[3] + w1 * (float)b[3];
    o1.x = w0 * (float)a[4] + w1 * (float)b[4];
    o1.y = w0 * (float)a[5] + w1 * (float)b[5];
    o1.z = w0 * (float)a[6] + w1 * (float)b[6];
    o1.w = w0 * (float)a[7] + w1 * (float)b[7];
    float4* dst = reinterpret_cast<float4*>(out + (size_t)t * HID + c * 8);
    dst[0] = o0;
    dst[1] = o1;
}

extern "C" void kernel_launch(void* const* d_in, const int* in_sizes, int n_in,
                              void* d_out, int out_size, void* d_ws, size_t ws_size,
                              hipStream_t stream) {
    const float* x  = (const float*)d_in[0];
    const float* gw = (const float*)d_in[1];
    const float* w1 = (const float*)d_in[2];
    const float* w2 = (const float*)d_in[3];
    float* out = (float*)d_out;
    char* ws = (char*)d_ws;

    int*    cnt       = (int*)(ws + 0);
    int*    cursor    = (int*)(ws + 64);
    int*    offs      = (int*)(ws + 128);
    int*    nmt       = (int*)(ws + 256);
    int*    ttab      = (int*)(ws + 512);
    int*    part_cnt  = (int*)(ws + 4096);
    double* part_sumP = (double*)(ws + 131072);
    int*    row_tok   = (int*)(ws + 262144);
    float*  row_w     = (float*)(ws + 327680);
    int*    tk_idx    = (int*)(ws + 393216);
    float*  tk_w      = (float*)(ws + 458752);
    int*    tok_row   = (int*)(ws + 524288);
    const size_t OFF = 589824;
    _Float16* xh  = (_Float16*)(ws + OFF);
    _Float16* w1t = (_Float16*)(ws + OFF + (1ull << 25));
    _Float16* w2t = (_Float16*)(ws + OFF + (2ull << 25));
    _Float16* hh  = (_Float16*)(ws + OFF + (3ull << 25));
    _Float16* y   = (_Float16*)(ws + OFF);   // aliases xh+w1t (dead after gemm1)

    prep_kernel<<<16384 + GATE_NB, 256, 0, stream>>>(x, gw, w1, xh, w1t,
                                                     tk_idx, tk_w, part_cnt, part_sumP);
    finalize_kernel<<<1, 256, 0, stream>>>(part_cnt, part_sumP, cnt, offs, cursor,
                                           ttab, nmt, out + (size_t)T_TOKENS * HID);
    scatter_kernel<<<T_TOKENS / 256, 256, 0, stream>>>(tk_idx, tk_w, offs, cursor,
                                                       row_tok, row_w, tok_row);

    // gemm1 + fused w2-tconv (w2t consumed only by the next kernel)
    gemmf_kernel<true, true, HID, INTERM / 128, true>
        <<<GEMM1_GRID + W2_BLOCKS, 256, 0, stream>>>(xh, w1t, cnt, offs, row_tok, ttab, nmt,
                                                     hh, INTERM, w2, w2t);
    // gemm2: m97-style single-buffer engine (A/B vs gemm1's counted-vmcnt engine)
    gemms_kernel<INTERM, HID / 128>
        <<<GEMM2_GRID, 256, 0, stream>>>(hh, w2t, cnt, offs, ttab, nmt, y, HID);

    combine_kernel<<<T_TOKENS, 256, 0, stream>>>(y, tok_row, tk_w, out);
}

// Round 14
// 333.733 us; speedup vs baseline: 1.1696x; 1.1173x over previous
//
#include <hip/hip_runtime.h>
#include <hip/hip_fp16.h>
#include <cmath>

#define T_TOKENS 8192
#define HID 2048
#define NEXP 8
#define INTERM 1024
#define GATE_NB 2048
#define MAX_TT 136
#define GEMM1_GRID (8 * 136)    // one block per item, XCD-affine
#define W2_BLOCKS 16384         // w2 tconv blocks appended to gemm1 dispatch
#define GEMM2_GRID (8 * 272)

typedef _Float16 f16x8 __attribute__((ext_vector_type(8)));
typedef _Float16 f16x4 __attribute__((ext_vector_type(4)));
typedef float f32x4 __attribute__((ext_vector_type(4)));

static __device__ __forceinline__ float gelu_tanh(float v) {
    return 0.5f * v * (1.0f + tanhf(0.79788456080286535588f * (v + 0.044715f * v * v * v)));
}

static __device__ __forceinline__ void glds16(const void* g, void* l) {
    __builtin_amdgcn_global_load_lds((const __attribute__((address_space(1))) void*)g,
                                     (__attribute__((address_space(3))) void*)l, 16, 0, 0);
}

// 128B-row tiles (BK=64): phys 16B-chunk = chunk ^ (row&7)  [R9-verified, 0 conflicts]
static __device__ __forceinline__ f16x8 lds_read(const _Float16* base, int row, int chunk) {
    int phys = chunk ^ (row & 7);
    return *reinterpret_cast<const f16x8*>(
        reinterpret_cast<const char*>(base) + row * 128 + phys * 16);
}

// ------------- tconv body: fp32 [Z][R][C] -> fp16 [Z][C][R] (shared buf passed in) -------------
static __device__ __forceinline__ void tconv_body(const float* __restrict__ in,
                                                  _Float16* __restrict__ out,
                                                  int R, int C, int bx, int by, int bz,
                                                  float* __restrict__ t /* [32*33] */) {
    int r0 = by * 32, c0 = bx * 32;
    int tid = threadIdx.x;
    int r = tid >> 3, c4 = (tid & 7) * 4;
    const float4 v = *reinterpret_cast<const float4*>(&in[((size_t)bz * R + (r0 + r)) * C + c0 + c4]);
    t[r * 33 + c4 + 0] = v.x; t[r * 33 + c4 + 1] = v.y;
    t[r * 33 + c4 + 2] = v.z; t[r * 33 + c4 + 3] = v.w;
    __syncthreads();
    int oc = tid >> 3;
    int or4 = (tid & 7) * 4;
    f16x4 o;
    o[0] = (_Float16)t[(or4 + 0) * 33 + oc];
    o[1] = (_Float16)t[(or4 + 1) * 33 + oc];
    o[2] = (_Float16)t[(or4 + 2) * 33 + oc];
    o[3] = (_Float16)t[(or4 + 3) * 33 + oc];
    *reinterpret_cast<f16x4*>(&out[((size_t)bz * C + (c0 + oc)) * R + r0 + or4]) = o;
}

// -------- gate body: one wave per token; emits xh = fp16(x) --------
static __device__ __forceinline__ void gate_body(const float* __restrict__ x,
                                                 const float* __restrict__ gw,
                                                 _Float16* __restrict__ xh,
                                                 int* __restrict__ tk_idx, float* __restrict__ tk_w,
                                                 int* __restrict__ part_cnt,
                                                 double* __restrict__ part_sumP, int gid) {
    __shared__ double sds[4][NEXP];
    __shared__ int sci[4][NEXP];
    int w = threadIdx.x >> 6;
    int lane = threadIdx.x & 63;
    int t = gid * 4 + w;

    const float4* xr = (const float4*)(x + (size_t)t * HID);
    _Float16* xo = xh + (size_t)t * HID;
    double acc[NEXP];
#pragma unroll
    for (int e = 0; e < NEXP; e++) acc[e] = 0.0;
#pragma unroll
    for (int i = 0; i < HID / 256; i++) {
        float4 xv = xr[i * 64 + lane];
        f16x4 h;
        h[0] = (_Float16)xv.x; h[1] = (_Float16)xv.y;
        h[2] = (_Float16)xv.z; h[3] = (_Float16)xv.w;
        *reinterpret_cast<f16x4*>(xo + i * 256 + lane * 4) = h;
#pragma unroll
        for (int e = 0; e < NEXP; e++) {
            float4 gv = ((const float4*)(gw + (size_t)e * HID))[i * 64 + lane];
            acc[e] += (double)xv.x * (double)gv.x + (double)xv.y * (double)gv.y
                    + (double)xv.z * (double)gv.z + (double)xv.w * (double)gv.w;
        }
    }
#pragma unroll
    for (int e = 0; e < NEXP; e++) {
#pragma unroll
        for (int off = 32; off > 0; off >>= 1) acc[e] += __shfl_xor(acc[e], off, 64);
    }
    double mx = acc[0];
#pragma unroll
    for (int e = 1; e < NEXP; e++) mx = acc[e] > mx ? acc[e] : mx;
    double ex[NEXP];
    double sum = 0.0;
#pragma unroll
    for (int e = 0; e < NEXP; e++) { ex[e] = exp(acc[e] - mx); sum += ex[e]; }
    int i0 = 0;
#pragma unroll
    for (int e = 1; e < NEXP; e++) if (ex[e] > ex[i0]) i0 = e;
    int i1 = (i0 == 0) ? 1 : 0;
#pragma unroll
    for (int e = 0; e < NEXP; e++) if (e != i0 && ex[e] > ex[i1]) i1 = e;
    double p0 = ex[i0], p1 = ex[i1];
    double t2 = p0 + p1;
    if (lane == 0) {
        tk_idx[2 * t] = i0; tk_idx[2 * t + 1] = i1;
        tk_w[2 * t] = (float)(p0 / t2); tk_w[2 * t + 1] = (float)(p1 / t2);
#pragma unroll
        for (int e = 0; e < NEXP; e++) {
            sds[w][e] = ex[e] / sum;
            sci[w][e] = (e == i0 ? 1 : 0) + (e == i1 ? 1 : 0);
        }
    }
    __syncthreads();
    if (threadIdx.x < NEXP) {
        int e = threadIdx.x;
        part_sumP[e * GATE_NB + gid] = sds[0][e] + sds[1][e] + sds[2][e] + sds[3][e];
        part_cnt[e * GATE_NB + gid]  = sci[0][e] + sci[1][e] + sci[2][e] + sci[3][e];
    }
}

// -------- prep: [0,16384) tconv w1, [16384,18432) gate --------
__global__ __launch_bounds__(256) void prep_kernel(const float* __restrict__ x,
                                                   const float* __restrict__ gw,
                                                   const float* __restrict__ w1,
                                                   _Float16* __restrict__ xh,
                                                   _Float16* __restrict__ w1t,
                                                   int* __restrict__ tk_idx, float* __restrict__ tk_w,
                                                   int* __restrict__ part_cnt,
                                                   double* __restrict__ part_sumP) {
    __shared__ float tsh[32 * 33];
    int bid = blockIdx.x;
    if (bid < 16384) {
        int bx = bid & 31, by = (bid >> 5) & 63, bz = bid >> 11;
        tconv_body(w1, w1t, HID, INTERM, bx, by, bz, tsh);
    } else {
        gate_body(x, gw, xh, tk_idx, tk_w, part_cnt, part_sumP, bid - 16384);
    }
}

// ------- reduce partials, offsets, aux, cursor, tile table (BM=128) -------
__global__ __launch_bounds__(256) void finalize_kernel(const int* __restrict__ part_cnt,
                                                       const double* __restrict__ part_sumP,
                                                       int* __restrict__ cnt, int* __restrict__ offs,
                                                       int* __restrict__ cursor,
                                                       int* __restrict__ ttab,
                                                       int* __restrict__ nmt,
                                                       float* __restrict__ aux_out) {
    __shared__ double swv[4];
    __shared__ int cwv[4];
    __shared__ double sE[NEXP];
    __shared__ int cE[NEXP];
    int w = threadIdx.x >> 6;
    int lane = threadIdx.x & 63;
    for (int e = 0; e < NEXP; e++) {
        double s = 0.0; int c = 0;
        for (int j = threadIdx.x; j < GATE_NB; j += 256) {
            s += part_sumP[e * GATE_NB + j];
            c += part_cnt[e * GATE_NB + j];
        }
#pragma unroll
        for (int off = 32; off > 0; off >>= 1) {
            s += __shfl_xor(s, off, 64);
            c += __shfl_xor(c, off, 64);
        }
        if (lane == 0) { swv[w] = s; cwv[w] = c; }
        __syncthreads();
        if (threadIdx.x == 0) {
            sE[e] = swv[0] + swv[1] + swv[2] + swv[3];
            cE[e] = cwv[0] + cwv[1] + cwv[2] + cwv[3];
        }
        __syncthreads();
    }
    if (threadIdx.x == 0) {
        int off = 0;
        double aux = 0.0;
        int idx = 0;
#pragma unroll
        for (int e = 0; e < NEXP; e++) {
            cnt[e] = cE[e];
            offs[e] = off;
            off += cE[e];
            cursor[e] = 0;
            aux += ((double)cE[e] / (double)T_TOKENS) * (sE[e] / (double)T_TOKENS);
            int mt = (cE[e] + 127) >> 7;
            for (int m = 0; m < mt; m++) ttab[idx++] = (e << 16) | m;
        }
        nmt[0] = idx;
        for (; idx < MAX_TT; idx++) ttab[idx] = -1;
        aux_out[0] = (float)(0.01 * (double)NEXP * aux);
    }
}

// ------- build per-expert row lists + inverse map (wave-aggregated atomics) -------
__global__ void scatter_kernel(const int* __restrict__ tk_idx, const float* __restrict__ tk_w,
                               const int* __restrict__ offs, int* __restrict__ cursor,
                               int* __restrict__ row_tok, float* __restrict__ row_w,
                               int* __restrict__ tok_row) {
    int t = blockIdx.x * blockDim.x + threadIdx.x;
    int lane = threadIdx.x & 63;
    unsigned long long below = (lane == 0) ? 0ull : ((~0ull) >> (64 - lane));
    for (int k = 0; k < 2; k++) {
        int e = tk_idx[2 * t + k];
        float wv = tk_w[2 * t + k];
        int pos = 0;
#pragma unroll
        for (int ee = 0; ee < NEXP; ee++) {
            unsigned long long m = __ballot(e == ee);
            if (e == ee) {
                int rank = (int)__popcll(m & below);
                int leader = (int)__ffsll((unsigned long long)m) - 1;
                int b = 0;
                if (lane == leader) b = atomicAdd(&cursor[ee], (int)__popcll(m));
                b = __shfl(b, leader, 64);
                pos = b + rank;
            }
        }
        int r = offs[e] + pos;
        row_tok[r] = t;
        row_w[r] = wv;
        tok_row[2 * t + k] = r;
    }
}

// ====== Grouped GEMM: 128x128 tile, BK=64, SINGLE-buffer, syncthreads-only ======
// 32KB LDS -> 4 blocks/CU. Per K-tile: 8 glds -> __syncthreads (compiler drains
// vmcnt) -> 2 ks-phases of {8 ds_read + 16 MFMA, compiler-scheduled lgkm waits}
// -> __syncthreads. Cross-block overlap (m114) covers the drain stall; no asm pins.
template<bool GATHER, bool GELU, int KTOT, int NX, bool FUSE>
__global__ __launch_bounds__(256, 4) void gemmk_kernel(
    const _Float16* __restrict__ Aglob,
    const _Float16* __restrict__ Bglob,
    const int* __restrict__ cnt, const int* __restrict__ offs,
    const int* __restrict__ row_tok,
    const int* __restrict__ ttab,
    const int* __restrict__ nmt,
    _Float16* __restrict__ Out, int Ncols,
    const float* __restrict__ w2in, _Float16* __restrict__ w2out)
{
    constexpr int NT = KTOT / 64;
    __shared__ __align__(16) _Float16 As[128][64];   // 16KB
    __shared__ __align__(16) _Float16 Bs[128][64];   // 16KB

    if (FUSE && blockIdx.x >= GEMM1_GRID) {
        int b = blockIdx.x - GEMM1_GRID;
        int bx = b & 63, by = (b >> 6) & 31, bz = b >> 11;   // w2: R=INTERM, C=HID
        tconv_body(w2in, w2out, INTERM, HID, bx, by, bz,
                   reinterpret_cast<float*>(&As[0][0]));
        return;
    }

    int n_items = nmt[0] * NX;
    int chunk = (n_items + 7) >> 3;
    int xcd = blockIdx.x & 7;
    int i = blockIdx.x >> 3;
    if (i >= chunk) return;
    int it = xcd * chunk + i;
    if (it >= n_items) return;

    int tid = threadIdx.x;
    int w = tid >> 6, lane = tid & 63;
    int wr = w >> 1, wc = w & 1;          // 2x2 wave grid, wave-tile 64x64
    int fr = lane & 15, fq = lane >> 4;

    int srow = lane >> 3;                 // 0..7: row within one glds (128B rows)
    int lc = (lane & 7) ^ srow;           // pre-swizzled 16B chunk

    _Float16* ldsA = &As[w * 32][0];      // wave stages A rows [32w, 32w+32)
    _Float16* ldsB = &Bs[w * 32][0];

    int ent = ttab[it / NX];
    int e = ent >> 16;
    int m0 = (ent & 0xffff) << 7;
    int Ne = cnt[e];
    int base = offs[e];
    int n0 = (it & (NX - 1)) << 7;

    const _Float16* aS[4];
#pragma unroll
    for (int g = 0; g < 4; g++) {
        int ar = m0 + w * 32 + g * 8 + srow; if (ar >= Ne) ar = Ne - 1;
        int id = GATHER ? row_tok[base + ar] : (base + ar);
        aS[g] = Aglob + (size_t)id * KTOT + lc * 8;
    }
    const size_t bexp = (size_t)e * Ncols * KTOT;
    const _Float16* bS[4];
#pragma unroll
    for (int g = 0; g < 4; g++)
        bS[g] = Bglob + bexp + (size_t)(n0 + w * 32 + g * 8 + srow) * KTOT + lc * 8;

    f32x4 acc[4][4] = {};

    for (int j = 0; j < NT; ++j) {
        int koff = j * 64;
#pragma unroll
        for (int g = 0; g < 4; g++) glds16(aS[g] + koff, ldsA + g * 512);
#pragma unroll
        for (int g = 0; g < 4; g++) glds16(bS[g] + koff, ldsB + g * 512);
        __syncthreads();                  // compiler drains vmcnt before barrier

#pragma unroll
        for (int ks = 0; ks < 2; ks++) {
            f16x8 a_[4], b_[4];
#pragma unroll
            for (int ii = 0; ii < 4; ii++)
                a_[ii] = lds_read(&As[0][0], wr * 64 + ii * 16 + fr, ks * 4 + fq);
#pragma unroll
            for (int jj = 0; jj < 4; jj++)
                b_[jj] = lds_read(&Bs[0][0], wc * 64 + jj * 16 + fr, ks * 4 + fq);
#pragma unroll
            for (int ii = 0; ii < 4; ii++)
#pragma unroll
                for (int jj = 0; jj < 4; jj++)
                    acc[ii][jj] = __builtin_amdgcn_mfma_f32_16x16x32_f16(
                        a_[ii], b_[jj], acc[ii][jj], 0, 0, 0);
        }
        __syncthreads();                  // protect buffer reuse
    }

    // ---- epilogue ----
#pragma unroll
    for (int mi = 0; mi < 4; mi++) {
#pragma unroll
        for (int r = 0; r < 4; r++) {
            int row = m0 + wr * 64 + mi * 16 + fq * 4 + r;
            if (row < Ne) {
                _Float16* dst = Out + (size_t)(base + row) * Ncols + n0 + wc * 64 + fr;
#pragma unroll
                for (int ni = 0; ni < 4; ni++) {
                    float v = acc[mi][ni][r];
                    if (GELU) v = gelu_tanh(v);
                    dst[ni * 16] = (_Float16)v;
                }
            }
        }
    }
}

// ---------------- combine: out[t] = w0*y[r0] + w1*y[r1] ----------------
__global__ __launch_bounds__(256) void combine_kernel(const _Float16* __restrict__ y,
                                                      const int* __restrict__ tok_row,
                                                      const float* __restrict__ tk_w,
                                                      float* __restrict__ out) {
    int t = blockIdx.x;
    int c = threadIdx.x;
    int r0 = tok_row[2 * t], r1 = tok_row[2 * t + 1];
    float w0 = tk_w[2 * t], w1 = tk_w[2 * t + 1];
    f16x8 a = reinterpret_cast<const f16x8*>(y + (size_t)r0 * HID)[c];
    f16x8 b = reinterpret_cast<const f16x8*>(y + (size_t)r1 * HID)[c];
    float4 o0, o1;
    o0.x = w0 * (float)a[0] + w1 * (float)b[0];
    o0.y = w0 * (float)a[1] + w1 * (float)b[1];
    o0.z = w0 * (float)a[2] + w1 * (float)b[2];
    o0.w = w0 * (float)a[3] + w1 * (float)b[3];
    o1.x = w0 * (float)a[4] + w1 * (float)b[4];
    o1.y = w0 * (float)a[5] + w1 * (float)b[5];
    o1.z = w0 * (float)a[6] + w1 * (float)b[6];
    o1.w = w0 * (float)a[7] + w1 * (float)b[7];
    float4* dst = reinterpret_cast<float4*>(out + (size_t)t * HID + c * 8);
    dst[0] = o0;
    dst[1] = o1;
}

extern "C" void kernel_launch(void* const* d_in, const int* in_sizes, int n_in,
                              void* d_out, int out_size, void* d_ws, size_t ws_size,
                              hipStream_t stream) {
    const float* x  = (const float*)d_in[0];
    const float* gw = (const float*)d_in[1];
    const float* w1 = (const float*)d_in[2];
    const float* w2 = (const float*)d_in[3];
    float* out = (float*)d_out;
    char* ws = (char*)d_ws;

    int*    cnt       = (int*)(ws + 0);
    int*    cursor    = (int*)(ws + 64);
    int*    offs      = (int*)(ws + 128);
    int*    nmt       = (int*)(ws + 256);
    int*    ttab      = (int*)(ws + 512);
    int*    part_cnt  = (int*)(ws + 4096);
    double* part_sumP = (double*)(ws + 131072);
    int*    row_tok   = (int*)(ws + 262144);
    float*  row_w     = (float*)(ws + 327680);
    int*    tk_idx    = (int*)(ws + 393216);
    float*  tk_w      = (float*)(ws + 458752);
    int*    tok_row   = (int*)(ws + 524288);
    const size_t OFF = 589824;
    _Float16* xh  = (_Float16*)(ws + OFF);
    _Float16* w1t = (_Float16*)(ws + OFF + (1ull << 25));
    _Float16* w2t = (_Float16*)(ws + OFF + (2ull << 25));
    _Float16* hh  = (_Float16*)(ws + OFF + (3ull << 25));
    _Float16* y   = (_Float16*)(ws + OFF);   // aliases xh+w1t (dead after gemm1)

    prep_kernel<<<16384 + GATE_NB, 256, 0, stream>>>(x, gw, w1, xh, w1t,
                                                     tk_idx, tk_w, part_cnt, part_sumP);
    finalize_kernel<<<1, 256, 0, stream>>>(part_cnt, part_sumP, cnt, offs, cursor,
                                           ttab, nmt, out + (size_t)T_TOKENS * HID);
    scatter_kernel<<<T_TOKENS / 256, 256, 0, stream>>>(tk_idx, tk_w, offs, cursor,
                                                       row_tok, row_w, tok_row);

    // gemm1 (BK=64 single-buffer engine) + fused w2-tconv blocks
    gemmk_kernel<true, true, HID, INTERM / 128, true>
        <<<GEMM1_GRID + W2_BLOCKS, 256, 0, stream>>>(xh, w1t, cnt, offs, row_tok, ttab, nmt,
                                                     hh, INTERM, w2, w2t);
    // gemm2: same engine, no gather/gelu
    gemmk_kernel<false, false, INTERM, HID / 128, false>
        <<<GEMM2_GRID, 256, 0, stream>>>(hh, w2t, cnt, offs, row_tok, ttab, nmt,
                                         y, HID, nullptr, nullptr);

    combine_kernel<<<T_TOKENS, 256, 0, stream>>>(y, tok_row, tk_w, out);
}